// Round 23
// baseline (98.929 us; speedup 1.0000x reference)
//
#include <hip/hip_runtime.h>

#define N_NODES 50000
#define N_EDGES 1600000
#define HEADS 4
#define DPH 16
#define F_IN 128
#define HD 64   // HEADS * DPH

#define NB 196            // buckets: b = dst >> 8  (49999>>8 = 195)
#define PB 256            // partition blocks (round-16 measured-best)
#define EPP 6250          // edges per partition block
#define SLAB_CAP 72       // mean 32 + 7 sigma
#define TILE 2048

#define QKV_BLOCKS 3125   // 50000/16
#define FUSED_TOTAL 3385  // qkv blocks + partition slots (bx%13==12)

using bf16x8 = __attribute__((ext_vector_type(8))) short;
using f32x4  = __attribute__((ext_vector_type(4))) float;
using f32x2  = __attribute__((ext_vector_type(2))) float;

__device__ inline unsigned short bf16_rne(float f) {
    const unsigned u = __float_as_uint(f);
    return (unsigned short)((u + 0x7FFFu + ((u >> 16) & 1u)) >> 16);
}
__device__ inline unsigned pack_kv(float k, float v) {
    return ((unsigned)bf16_rne(v) << 16) | (unsigned)bf16_rne(k);
}

// ---------------------------------------------------------------------------
// Repack W into MFMA B-fragment order (round-14 proven). Block 0 also zeroes
// ghist (replaces the standalone memset launch; stream-ordered before use).
// ---------------------------------------------------------------------------
__global__ void repack_w(const float* __restrict__ Wq,
                         const float* __restrict__ Wk,
                         const float* __restrict__ Wv,
                         uint4* __restrict__ Wpk,
                         int* __restrict__ ghist) {
    const int tile = blockIdx.x;          // 0..11 = mat*4 + cb
    const int tid = threadIdx.x;
    if (tile == 0 && tid < NB) ghist[tid] = 0;
    const int mat = tile >> 2, cb = tile & 3;
    const float* W = (mat == 0) ? Wq : (mat == 1) ? Wk : Wv;
    const int kg = tid >> 6, lane = tid & 63;
    const int kbase = kg * 32 + (lane >> 4) * 8;
    const int c = cb * 16 + (lane & 15);
    unsigned w[4];
    #pragma unroll
    for (int p = 0; p < 4; ++p) {
        const unsigned lo = bf16_rne(W[(kbase + 2 * p) * HD + c]);
        const unsigned hi = bf16_rne(W[(kbase + 2 * p + 1) * HD + c]);
        w[p] = (hi << 16) | lo;
    }
    Wpk[(tile * 4 + kg) * 64 + lane] = make_uint4(w[0], w[1], w[2], w[3]);
}

// ---------------------------------------------------------------------------
// Fused: qkv-MFMA role || radix-partition role (round-22 exact).
// ---------------------------------------------------------------------------
__global__ void __launch_bounds__(256)
qkv_and_partition(const float* __restrict__ x,
                  const uint4* __restrict__ Wpk,
                  const int* __restrict__ src,
                  const int* __restrict__ dst,
                  unsigned short* __restrict__ Qb,
                  unsigned* __restrict__ KV,
                  unsigned* __restrict__ slab,
                  int* __restrict__ gcnt,
                  int* __restrict__ ghist) {
    const int bx = blockIdx.x;
    const int tid = threadIdx.x;

    __shared__ union {
        float xs[16][132];                       // qkv role (8448 B)
        struct {                                 // partition role (~13.3 KB)
            unsigned sbuf[TILE];
            unsigned char bp[TILE];
            int cnt[256];
            int toff[256];
            int gcur[256];
            int wsum[4];
        } p;
    } sm;

    if ((bx % 13) == 12) {
        // ---- partition role ----
        const int pid = bx / 13;
        if (pid >= PB) return;
        sm.p.gcur[tid] = 0;
        __syncthreads();

        const int lo = pid * EPP;
        for (int tb = 0; tb < EPP; tb += TILE) {
            const int tcnt = min(TILE, EPP - tb);
            sm.p.cnt[tid] = 0;
            __syncthreads();

            // load + rank (regs)
            unsigned rec[8]; int bb[8], rk[8];
            #pragma unroll
            for (int j = 0; j < 8; ++j) {
                const int ol = tid + j * 256;
                if (ol < tcnt) {
                    const int i = lo + tb + ol;
                    const int s = src[i], d = dst[i];
                    bb[j] = d >> 8;
                    rec[j] = ((unsigned)s << 8) | (unsigned)(d & 255);
                    rk[j] = atomicAdd(&sm.p.cnt[bb[j]], 1);
                } else bb[j] = -1;
            }
            __syncthreads();

            // 256-wide exclusive scan of cnt -> toff
            const int lane = tid & 63, wv = tid >> 6;
            const int v = sm.p.cnt[tid];
            int incl = v;
            #pragma unroll
            for (int s = 1; s < 64; s <<= 1) {
                const int t = __shfl_up(incl, s, 64);
                if (lane >= s) incl += t;
            }
            if (lane == 63) sm.p.wsum[wv] = incl;
            __syncthreads();
            if (tid == 0) {
                int a = 0;
                #pragma unroll
                for (int i = 0; i < 4; ++i) { const int t = sm.p.wsum[i]; sm.p.wsum[i] = a; a += t; }
            }
            __syncthreads();
            sm.p.toff[tid] = sm.p.wsum[wv] + incl - v;
            __syncthreads();

            // scatter into LDS in bucket order
            #pragma unroll
            for (int j = 0; j < 8; ++j) {
                if (bb[j] >= 0) {
                    const int p = sm.p.toff[bb[j]] + rk[j];
                    sm.p.sbuf[p] = rec[j];
                    sm.p.bp[p] = (unsigned char)bb[j];
                }
            }
            __syncthreads();

            // linear copy-out: consecutive lanes -> consecutive slab addrs
            for (int o = tid; o < tcnt; o += 256) {
                const int b = sm.p.bp[o];
                const int gpos = sm.p.gcur[b] + (o - sm.p.toff[b]);
                if (gpos < SLAB_CAP)
                    slab[((size_t)b * PB + pid) * SLAB_CAP + gpos] = sm.p.sbuf[o];
            }
            __syncthreads();
            sm.p.gcur[tid] += sm.p.cnt[tid];
            __syncthreads();
        }

        if (tid < NB) {
            const int c = min(sm.p.gcur[tid], SLAB_CAP);
            gcnt[tid * PB + pid] = c;
            atomicAdd(&ghist[tid], c);
        }
        return;
    }

    // ---- qkv role (MFMA, round-14 verbatim; Q stored bf16) ----
    const int qb = bx - bx / 13;         // dense id: skips all %13==12 slots
    const int node0 = qb * 16;

    for (int i = tid; i < 512; i += 256) {          // 512 float4 = 16 x 32
        const int r = i >> 5, c4 = (i & 31) * 4;
        *(float4*)&sm.xs[r][c4] = *(const float4*)&x[(size_t)(node0 + r) * F_IN + c4];
    }
    __syncthreads();

    const int w = tid >> 6;              // wave = col block (0..3)
    const int lane = tid & 63;
    const int row = lane & 15;
    const int kb = (lane >> 4) * 8;

    bf16x8 a[4];
    #pragma unroll
    for (int kg = 0; kg < 4; ++kg) {
        const float4 fa = *(const float4*)&sm.xs[row][kg * 32 + kb];
        const float4 fb = *(const float4*)&sm.xs[row][kg * 32 + kb + 4];
        a[kg][0] = (short)bf16_rne(fa.x); a[kg][1] = (short)bf16_rne(fa.y);
        a[kg][2] = (short)bf16_rne(fa.z); a[kg][3] = (short)bf16_rne(fa.w);
        a[kg][4] = (short)bf16_rne(fb.x); a[kg][5] = (short)bf16_rne(fb.y);
        a[kg][6] = (short)bf16_rne(fb.z); a[kg][7] = (short)bf16_rne(fb.w);
    }

    const bf16x8* Wp = (const bf16x8*)Wpk;
    f32x4 accQ = {0.f, 0.f, 0.f, 0.f};
    f32x4 accK = {0.f, 0.f, 0.f, 0.f};
    f32x4 accV = {0.f, 0.f, 0.f, 0.f};
    #pragma unroll
    for (int kg = 0; kg < 4; ++kg) {
        accQ = __builtin_amdgcn_mfma_f32_16x16x32_bf16(
            a[kg], Wp[((0 * 4 + w) * 4 + kg) * 64 + lane], accQ, 0, 0, 0);
        accK = __builtin_amdgcn_mfma_f32_16x16x32_bf16(
            a[kg], Wp[((1 * 4 + w) * 4 + kg) * 64 + lane], accK, 0, 0, 0);
        accV = __builtin_amdgcn_mfma_f32_16x16x32_bf16(
            a[kg], Wp[((2 * 4 + w) * 4 + kg) * 64 + lane], accV, 0, 0, 0);
    }

    const int crow0 = (lane >> 4) * 4;
    const int ccol = w * 16 + (lane & 15);
    #pragma unroll
    for (int r = 0; r < 4; ++r) {
        const int n = node0 + crow0 + r;
        Qb[(size_t)n * HD + ccol] = bf16_rne(accQ[r]);
        KV[(size_t)n * HD + ccol] = pack_kv(accK[r], accV[r]);
    }
}

// ---------------------------------------------------------------------------
// bucket_csr (round-16 exact, PB=256 => one chunk per thread).
// ---------------------------------------------------------------------------
__global__ void __launch_bounds__(256)
bucket_csr(const unsigned* __restrict__ slab,
           const int* __restrict__ gcnt,
           const int* __restrict__ ghist,
           int* __restrict__ off,
           int* __restrict__ esrc) {
    const int b = blockIdx.x;
    const int tid = threadIdx.x;
    __shared__ int hist_s[NB];
    __shared__ int deg[256], cursor[256];
    __shared__ int wsum[4];
    __shared__ int base_s;

    if (tid < NB) hist_s[tid] = ghist[tid];
    deg[tid] = 0;
    __syncthreads();
    if (tid == 0) {
        int s = 0;
        for (int i = 0; i < b; ++i) s += hist_s[i];
        base_s = s;
    }

    const int myc = gcnt[b * PB + tid];
    const unsigned* myslab = slab + ((size_t)b * PB + tid) * SLAB_CAP;

    for (int c = 0; c < myc; ++c) atomicAdd(&deg[(int)(myslab[c] & 255u)], 1);
    __syncthreads();

    const int lane = tid & 63, wv = tid >> 6;
    const int v = deg[tid];
    int incl = v;
    #pragma unroll
    for (int s = 1; s < 64; s <<= 1) {
        const int t = __shfl_up(incl, s, 64);
        if (lane >= s) incl += t;
    }
    if (lane == 63) wsum[wv] = incl;
    __syncthreads();
    if (tid == 0) {
        int a = 0;
        #pragma unroll
        for (int i = 0; i < 4; ++i) { const int t = wsum[i]; wsum[i] = a; a += t; }
    }
    __syncthreads();
    const int ex = wsum[wv] + incl - v;
    cursor[tid] = ex;

    const int base = base_s;
    const int n = b * 256 + tid;
    if (n <= N_NODES) off[n] = base + ex;
    __syncthreads();

    for (int c = 0; c < myc; ++c) {
        const unsigned r = myslab[c];
        const int pos = atomicAdd(&cursor[(int)(r & 255u)], 1);
        esrc[base + pos] = (int)(r >> 8);
    }
}

// ---------------------------------------------------------------------------
// Gather (round-22 structure + f32x2-packed math): dot and accumulate run
// as ext_vector_type(2) ops so LLVM can emit v_pk_fma_f32 (2 FMA/instr on
// CDNA2+) — 16 pk_fma replaces 32 scalar FMA per iteration. Numerically
// identical; falls back to identical scalar code if not packed.
// ---------------------------------------------------------------------------
__global__ void __launch_bounds__(256)
gather_csr(const int* __restrict__ off,
           const int* __restrict__ esrc,
           const unsigned short* __restrict__ Qb,
           const unsigned* __restrict__ KV,
           float* __restrict__ out) {
    const int n = blockIdx.x * 4 + (threadIdx.x >> 6);
    if (n >= N_NODES) return;
    const int lane = threadIdx.x & 63;
    const int t = lane >> 2;
    const int h = lane & 3;
    const int beg = off[n];
    const int end = off[n + 1];

    f32x2 qv2[8];
    {
        const uint4* qp = (const uint4*)(Qb + (size_t)n * HD + h * DPH);
        const uint4 q0 = qp[0], q1 = qp[1];
        const unsigned qw[8] = {q0.x, q0.y, q0.z, q0.w, q1.x, q1.y, q1.z, q1.w};
        #pragma unroll
        for (int j = 0; j < 8; ++j) {
            qv2[j][0] = __uint_as_float(qw[j] << 16);
            qv2[j][1] = __uint_as_float(qw[j] & 0xFFFF0000u);
        }
    }

    f32x2 acc2[8];
    #pragma unroll
    for (int j = 0; j < 8; ++j) acc2[j] = (f32x2){0.f, 0.f};
    float zacc = 0.f;

    // prefetched src id for the current iteration (clamped read is safe:
    // invalid lanes contribute sc=0)
    int s_cur = (beg < end) ? esrc[min(beg + t, end - 1)] : 0;

    for (int base = beg; base < end; base += 16) {
        const bool valid = (base + t) < end;
        const int s = s_cur;
        if (base + 16 < end)
            s_cur = esrc[min(base + 16 + t, end - 1)];   // prefetch next iter

        const uint4* kp = (const uint4*)(KV + (size_t)s * HD + h * DPH);
        const uint4 w0 = kp[0], w1 = kp[1], w2 = kp[2], w3 = kp[3];
        const unsigned kw[16] = {w0.x, w0.y, w0.z, w0.w,
                                 w1.x, w1.y, w1.z, w1.w,
                                 w2.x, w2.y, w2.z, w2.w,
                                 w3.x, w3.y, w3.z, w3.w};
        // unpack each dim pair into f32x2 lanes
        f32x2 kk[8], vv[8];
        #pragma unroll
        for (int j = 0; j < 8; ++j) {
            kk[j][0] = __uint_as_float(kw[2 * j + 0] << 16);
            kk[j][1] = __uint_as_float(kw[2 * j + 1] << 16);
            vv[j][0] = __uint_as_float(kw[2 * j + 0] & 0xFFFF0000u);
            vv[j][1] = __uint_as_float(kw[2 * j + 1] & 0xFFFF0000u);
        }
        f32x2 p2 = (f32x2){0.f, 0.f};
        #pragma unroll
        for (int j = 0; j < 8; ++j) p2 += kk[j] * qv2[j];   // v_pk_fma_f32
        float p = p2[0] + p2[1];
        p = fminf(fmaxf(p * 0.25f, -5.f), 5.f);
        float sc = __expf(p);
        sc = valid ? sc : 0.f;
        const f32x2 sc2 = (f32x2){sc, sc};
        #pragma unroll
        for (int j = 0; j < 8; ++j) acc2[j] += sc2 * vv[j]; // v_pk_fma_f32
        zacc += sc;
    }

    float acc[16];
    #pragma unroll
    for (int j = 0; j < 8; ++j) { acc[2 * j] = acc2[j][0]; acc[2 * j + 1] = acc2[j][1]; }

    // Reduce-scatter over t bits (masks 32,16,8,4 -> element bits 3,2,1,0).
    {
        const bool b = (lane & 32) != 0;
        float send[8], keep[8];
        #pragma unroll
        for (int j = 0; j < 8; ++j) {
            send[j] = b ? acc[j] : acc[j + 8];
            keep[j] = b ? acc[j + 8] : acc[j];
        }
        #pragma unroll
        for (int j = 0; j < 8; ++j) acc[j] = keep[j] + __shfl_xor(send[j], 32, 64);
    }
    {
        const bool b = (lane & 16) != 0;
        float send[4], keep[4];
        #pragma unroll
        for (int j = 0; j < 4; ++j) {
            send[j] = b ? acc[j] : acc[j + 4];
            keep[j] = b ? acc[j + 4] : acc[j];
        }
        #pragma unroll
        for (int j = 0; j < 4; ++j) acc[j] = keep[j] + __shfl_xor(send[j], 16, 64);
    }
    {
        const bool b = (lane & 8) != 0;
        float send[2], keep[2];
        #pragma unroll
        for (int j = 0; j < 2; ++j) {
            send[j] = b ? acc[j] : acc[j + 2];
            keep[j] = b ? acc[j + 2] : acc[j];
        }
        #pragma unroll
        for (int j = 0; j < 2; ++j) acc[j] = keep[j] + __shfl_xor(send[j], 8, 64);
    }
    {
        const bool b = (lane & 4) != 0;
        const float send = b ? acc[0] : acc[1];
        const float keep = b ? acc[1] : acc[0];
        acc[0] = keep + __shfl_xor(send, 4, 64);
    }

    zacc += __shfl_xor(zacc, 4, 64);
    zacc += __shfl_xor(zacc, 8, 64);
    zacc += __shfl_xor(zacc, 16, 64);
    zacc += __shfl_xor(zacc, 32, 64);

    out[(size_t)n * HD + h * DPH + t] = acc[0] / (zacc + 1e-6f);
}

extern "C" void kernel_launch(void* const* d_in, const int* in_sizes, int n_in,
                              void* d_out, int out_size, void* d_ws, size_t ws_size,
                              hipStream_t stream) {
    const float* x   = (const float*)d_in[0];
    const int*   src = (const int*)d_in[1];
    const int*   dst = (const int*)d_in[2];
    const float* Wq  = (const float*)d_in[3];
    const float* Wk  = (const float*)d_in[4];
    const float* Wv  = (const float*)d_in[5];
    float* out = (float*)d_out;

    unsigned short* Qb = (unsigned short*)d_ws;                // 6.4 MB
    unsigned* KV    = (unsigned*)(Qb + (size_t)N_NODES * HD);  // 12.8 MB
    uint4*    Wpk   = (uint4*)(KV + (size_t)N_NODES * HD);     // 48 KB
    unsigned* slab  = (unsigned*)(Wpk + 12 * 4 * 64);          // 14.45 MB
    int*      gcnt  = (int*)(slab + (size_t)NB * PB * SLAB_CAP); // 200 KB
    int*      ghist = gcnt + NB * PB;                          // 784 B
    int*      off   = ghist + NB;                              // 200 KB
    int*      esrc  = off + (N_NODES + 1);                     // 6.4 MB

    repack_w<<<12, 256, 0, stream>>>(Wq, Wk, Wv, Wpk, ghist);
    qkv_and_partition<<<FUSED_TOTAL, 256, 0, stream>>>(x, Wpk, src, dst,
                                                       Qb, KV, slab, gcnt, ghist);
    bucket_csr<<<NB, 256, 0, stream>>>(slab, gcnt, ghist, off, esrc);
    gather_csr<<<(N_NODES + 3) / 4, 256, 0, stream>>>(off, esrc, Qb, KV, out);
}

// Round 24
// 98.033 us; speedup vs baseline: 1.0091x; 1.0091x over previous
//
#include <hip/hip_runtime.h>

#define N_NODES 50000
#define N_EDGES 1600000
#define HEADS 4
#define DPH 16
#define F_IN 128
#define HD 64   // HEADS * DPH

#define NB 196            // buckets: b = dst >> 8  (49999>>8 = 195)
#define PB 256            // partition blocks (round-16 measured-best)
#define EPP 6250          // edges per partition block
#define SLAB_CAP 72       // mean 32 + 7 sigma
#define TILE 2048

#define QKV_BLOCKS 3125   // 50000/16
#define FUSED_TOTAL 3385  // qkv blocks + partition slots (bx%13==12)

using bf16x8 = __attribute__((ext_vector_type(8))) short;
using f32x4  = __attribute__((ext_vector_type(4))) float;

__device__ inline unsigned short bf16_rne(float f) {
    const unsigned u = __float_as_uint(f);
    return (unsigned short)((u + 0x7FFFu + ((u >> 16) & 1u)) >> 16);
}
__device__ inline unsigned pack_kv(float k, float v) {
    return ((unsigned)bf16_rne(v) << 16) | (unsigned)bf16_rne(k);
}

// ---------------------------------------------------------------------------
// Repack W into MFMA B-fragment order (round-14 proven). Block 0 also zeroes
// ghist (replaces the standalone memset launch; stream-ordered before use).
// ---------------------------------------------------------------------------
__global__ void repack_w(const float* __restrict__ Wq,
                         const float* __restrict__ Wk,
                         const float* __restrict__ Wv,
                         uint4* __restrict__ Wpk,
                         int* __restrict__ ghist) {
    const int tile = blockIdx.x;          // 0..11 = mat*4 + cb
    const int tid = threadIdx.x;
    if (tile == 0 && tid < NB) ghist[tid] = 0;
    const int mat = tile >> 2, cb = tile & 3;
    const float* W = (mat == 0) ? Wq : (mat == 1) ? Wk : Wv;
    const int kg = tid >> 6, lane = tid & 63;
    const int kbase = kg * 32 + (lane >> 4) * 8;
    const int c = cb * 16 + (lane & 15);
    unsigned w[4];
    #pragma unroll
    for (int p = 0; p < 4; ++p) {
        const unsigned lo = bf16_rne(W[(kbase + 2 * p) * HD + c]);
        const unsigned hi = bf16_rne(W[(kbase + 2 * p + 1) * HD + c]);
        w[p] = (hi << 16) | lo;
    }
    Wpk[(tile * 4 + kg) * 64 + lane] = make_uint4(w[0], w[1], w[2], w[3]);
}

// ---------------------------------------------------------------------------
// Fused: qkv-MFMA role || radix-partition role (round-22 exact).
// ---------------------------------------------------------------------------
__global__ void __launch_bounds__(256)
qkv_and_partition(const float* __restrict__ x,
                  const uint4* __restrict__ Wpk,
                  const int* __restrict__ src,
                  const int* __restrict__ dst,
                  unsigned short* __restrict__ Qb,
                  unsigned* __restrict__ KV,
                  unsigned* __restrict__ slab,
                  int* __restrict__ gcnt,
                  int* __restrict__ ghist) {
    const int bx = blockIdx.x;
    const int tid = threadIdx.x;

    __shared__ union {
        float xs[16][132];                       // qkv role (8448 B)
        struct {                                 // partition role (~13.3 KB)
            unsigned sbuf[TILE];
            unsigned char bp[TILE];
            int cnt[256];
            int toff[256];
            int gcur[256];
            int wsum[4];
        } p;
    } sm;

    if ((bx % 13) == 12) {
        // ---- partition role ----
        const int pid = bx / 13;
        if (pid >= PB) return;
        sm.p.gcur[tid] = 0;
        __syncthreads();

        const int lo = pid * EPP;
        for (int tb = 0; tb < EPP; tb += TILE) {
            const int tcnt = min(TILE, EPP - tb);
            sm.p.cnt[tid] = 0;
            __syncthreads();

            // load + rank (regs)
            unsigned rec[8]; int bb[8], rk[8];
            #pragma unroll
            for (int j = 0; j < 8; ++j) {
                const int ol = tid + j * 256;
                if (ol < tcnt) {
                    const int i = lo + tb + ol;
                    const int s = src[i], d = dst[i];
                    bb[j] = d >> 8;
                    rec[j] = ((unsigned)s << 8) | (unsigned)(d & 255);
                    rk[j] = atomicAdd(&sm.p.cnt[bb[j]], 1);
                } else bb[j] = -1;
            }
            __syncthreads();

            // 256-wide exclusive scan of cnt -> toff
            const int lane = tid & 63, wv = tid >> 6;
            const int v = sm.p.cnt[tid];
            int incl = v;
            #pragma unroll
            for (int s = 1; s < 64; s <<= 1) {
                const int t = __shfl_up(incl, s, 64);
                if (lane >= s) incl += t;
            }
            if (lane == 63) sm.p.wsum[wv] = incl;
            __syncthreads();
            if (tid == 0) {
                int a = 0;
                #pragma unroll
                for (int i = 0; i < 4; ++i) { const int t = sm.p.wsum[i]; sm.p.wsum[i] = a; a += t; }
            }
            __syncthreads();
            sm.p.toff[tid] = sm.p.wsum[wv] + incl - v;
            __syncthreads();

            // scatter into LDS in bucket order
            #pragma unroll
            for (int j = 0; j < 8; ++j) {
                if (bb[j] >= 0) {
                    const int p = sm.p.toff[bb[j]] + rk[j];
                    sm.p.sbuf[p] = rec[j];
                    sm.p.bp[p] = (unsigned char)bb[j];
                }
            }
            __syncthreads();

            // linear copy-out: consecutive lanes -> consecutive slab addrs
            for (int o = tid; o < tcnt; o += 256) {
                const int b = sm.p.bp[o];
                const int gpos = sm.p.gcur[b] + (o - sm.p.toff[b]);
                if (gpos < SLAB_CAP)
                    slab[((size_t)b * PB + pid) * SLAB_CAP + gpos] = sm.p.sbuf[o];
            }
            __syncthreads();
            sm.p.gcur[tid] += sm.p.cnt[tid];
            __syncthreads();
        }

        if (tid < NB) {
            const int c = min(sm.p.gcur[tid], SLAB_CAP);
            gcnt[tid * PB + pid] = c;
            atomicAdd(&ghist[tid], c);
        }
        return;
    }

    // ---- qkv role (MFMA, round-14 verbatim; Q stored bf16) ----
    const int qb = bx - bx / 13;         // dense id: skips all %13==12 slots
    const int node0 = qb * 16;

    for (int i = tid; i < 512; i += 256) {          // 512 float4 = 16 x 32
        const int r = i >> 5, c4 = (i & 31) * 4;
        *(float4*)&sm.xs[r][c4] = *(const float4*)&x[(size_t)(node0 + r) * F_IN + c4];
    }
    __syncthreads();

    const int w = tid >> 6;              // wave = col block (0..3)
    const int lane = tid & 63;
    const int row = lane & 15;
    const int kb = (lane >> 4) * 8;

    bf16x8 a[4];
    #pragma unroll
    for (int kg = 0; kg < 4; ++kg) {
        const float4 fa = *(const float4*)&sm.xs[row][kg * 32 + kb];
        const float4 fb = *(const float4*)&sm.xs[row][kg * 32 + kb + 4];
        a[kg][0] = (short)bf16_rne(fa.x); a[kg][1] = (short)bf16_rne(fa.y);
        a[kg][2] = (short)bf16_rne(fa.z); a[kg][3] = (short)bf16_rne(fa.w);
        a[kg][4] = (short)bf16_rne(fb.x); a[kg][5] = (short)bf16_rne(fb.y);
        a[kg][6] = (short)bf16_rne(fb.z); a[kg][7] = (short)bf16_rne(fb.w);
    }

    const bf16x8* Wp = (const bf16x8*)Wpk;
    f32x4 accQ = {0.f, 0.f, 0.f, 0.f};
    f32x4 accK = {0.f, 0.f, 0.f, 0.f};
    f32x4 accV = {0.f, 0.f, 0.f, 0.f};
    #pragma unroll
    for (int kg = 0; kg < 4; ++kg) {
        accQ = __builtin_amdgcn_mfma_f32_16x16x32_bf16(
            a[kg], Wp[((0 * 4 + w) * 4 + kg) * 64 + lane], accQ, 0, 0, 0);
        accK = __builtin_amdgcn_mfma_f32_16x16x32_bf16(
            a[kg], Wp[((1 * 4 + w) * 4 + kg) * 64 + lane], accK, 0, 0, 0);
        accV = __builtin_amdgcn_mfma_f32_16x16x32_bf16(
            a[kg], Wp[((2 * 4 + w) * 4 + kg) * 64 + lane], accV, 0, 0, 0);
    }

    const int crow0 = (lane >> 4) * 4;
    const int ccol = w * 16 + (lane & 15);
    #pragma unroll
    for (int r = 0; r < 4; ++r) {
        const int n = node0 + crow0 + r;
        Qb[(size_t)n * HD + ccol] = bf16_rne(accQ[r]);
        KV[(size_t)n * HD + ccol] = pack_kv(accK[r], accV[r]);
    }
}

// ---------------------------------------------------------------------------
// bucket_csr (round-16 exact, PB=256 => one chunk per thread).
// ---------------------------------------------------------------------------
__global__ void __launch_bounds__(256)
bucket_csr(const unsigned* __restrict__ slab,
           const int* __restrict__ gcnt,
           const int* __restrict__ ghist,
           int* __restrict__ off,
           int* __restrict__ esrc) {
    const int b = blockIdx.x;
    const int tid = threadIdx.x;
    __shared__ int hist_s[NB];
    __shared__ int deg[256], cursor[256];
    __shared__ int wsum[4];
    __shared__ int base_s;

    if (tid < NB) hist_s[tid] = ghist[tid];
    deg[tid] = 0;
    __syncthreads();
    if (tid == 0) {
        int s = 0;
        for (int i = 0; i < b; ++i) s += hist_s[i];
        base_s = s;
    }

    const int myc = gcnt[b * PB + tid];
    const unsigned* myslab = slab + ((size_t)b * PB + tid) * SLAB_CAP;

    for (int c = 0; c < myc; ++c) atomicAdd(&deg[(int)(myslab[c] & 255u)], 1);
    __syncthreads();

    const int lane = tid & 63, wv = tid >> 6;
    const int v = deg[tid];
    int incl = v;
    #pragma unroll
    for (int s = 1; s < 64; s <<= 1) {
        const int t = __shfl_up(incl, s, 64);
        if (lane >= s) incl += t;
    }
    if (lane == 63) wsum[wv] = incl;
    __syncthreads();
    if (tid == 0) {
        int a = 0;
        #pragma unroll
        for (int i = 0; i < 4; ++i) { const int t = wsum[i]; wsum[i] = a; a += t; }
    }
    __syncthreads();
    const int ex = wsum[wv] + incl - v;
    cursor[tid] = ex;

    const int base = base_s;
    const int n = b * 256 + tid;
    if (n <= N_NODES) off[n] = base + ex;
    __syncthreads();

    for (int c = 0; c < myc; ++c) {
        const unsigned r = myslab[c];
        const int pos = atomicAdd(&cursor[(int)(r & 255u)], 1);
        esrc[base + pos] = (int)(r >> 8);
    }
}

// ---------------------------------------------------------------------------
// Gather (round-22 exact: 16-edge batch + esrc prefetch + bf16 Q; scalar
// interleaved unpack keeps live-set minimal -> VGPR 32, Occ ~66%).
// ---------------------------------------------------------------------------
__global__ void __launch_bounds__(256)
gather_csr(const int* __restrict__ off,
           const int* __restrict__ esrc,
           const unsigned short* __restrict__ Qb,
           const unsigned* __restrict__ KV,
           float* __restrict__ out) {
    const int n = blockIdx.x * 4 + (threadIdx.x >> 6);
    if (n >= N_NODES) return;
    const int lane = threadIdx.x & 63;
    const int t = lane >> 2;
    const int h = lane & 3;
    const int beg = off[n];
    const int end = off[n + 1];

    float qv[16];
    {
        const uint4* qp = (const uint4*)(Qb + (size_t)n * HD + h * DPH);
        const uint4 q0 = qp[0], q1 = qp[1];
        const unsigned qw[8] = {q0.x, q0.y, q0.z, q0.w, q1.x, q1.y, q1.z, q1.w};
        #pragma unroll
        for (int j = 0; j < 8; ++j) {
            qv[2 * j + 0] = __uint_as_float(qw[j] << 16);
            qv[2 * j + 1] = __uint_as_float(qw[j] & 0xFFFF0000u);
        }
    }

    float acc[16];
    #pragma unroll
    for (int j = 0; j < 16; ++j) acc[j] = 0.f;
    float zacc = 0.f;

    // prefetched src id for the current iteration (clamped read is safe:
    // invalid lanes contribute sc=0)
    int s_cur = (beg < end) ? esrc[min(beg + t, end - 1)] : 0;

    for (int base = beg; base < end; base += 16) {
        const bool valid = (base + t) < end;
        const int s = s_cur;
        if (base + 16 < end)
            s_cur = esrc[min(base + 16 + t, end - 1)];   // prefetch next iter

        const uint4* kp = (const uint4*)(KV + (size_t)s * HD + h * DPH);
        const uint4 w0 = kp[0], w1 = kp[1], w2 = kp[2], w3 = kp[3];
        const unsigned kw[16] = {w0.x, w0.y, w0.z, w0.w,
                                 w1.x, w1.y, w1.z, w1.w,
                                 w2.x, w2.y, w2.z, w2.w,
                                 w3.x, w3.y, w3.z, w3.w};
        float p = 0.f;
        #pragma unroll
        for (int j = 0; j < 16; ++j)
            p = fmaf(__uint_as_float(kw[j] << 16), qv[j], p);
        p = fminf(fmaxf(p * 0.25f, -5.f), 5.f);
        float sc = __expf(p);
        sc = valid ? sc : 0.f;
        #pragma unroll
        for (int j = 0; j < 16; ++j)
            acc[j] = fmaf(sc, __uint_as_float(kw[j] & 0xFFFF0000u), acc[j]);
        zacc += sc;
    }

    // Reduce-scatter over t bits (masks 32,16,8,4 -> element bits 3,2,1,0).
    {
        const bool b = (lane & 32) != 0;
        float send[8], keep[8];
        #pragma unroll
        for (int j = 0; j < 8; ++j) {
            send[j] = b ? acc[j] : acc[j + 8];
            keep[j] = b ? acc[j + 8] : acc[j];
        }
        #pragma unroll
        for (int j = 0; j < 8; ++j) acc[j] = keep[j] + __shfl_xor(send[j], 32, 64);
    }
    {
        const bool b = (lane & 16) != 0;
        float send[4], keep[4];
        #pragma unroll
        for (int j = 0; j < 4; ++j) {
            send[j] = b ? acc[j] : acc[j + 4];
            keep[j] = b ? acc[j + 4] : acc[j];
        }
        #pragma unroll
        for (int j = 0; j < 4; ++j) acc[j] = keep[j] + __shfl_xor(send[j], 16, 64);
    }
    {
        const bool b = (lane & 8) != 0;
        float send[2], keep[2];
        #pragma unroll
        for (int j = 0; j < 2; ++j) {
            send[j] = b ? acc[j] : acc[j + 2];
            keep[j] = b ? acc[j + 2] : acc[j];
        }
        #pragma unroll
        for (int j = 0; j < 2; ++j) acc[j] = keep[j] + __shfl_xor(send[j], 8, 64);
    }
    {
        const bool b = (lane & 4) != 0;
        const float send = b ? acc[0] : acc[1];
        const float keep = b ? acc[1] : acc[0];
        acc[0] = keep + __shfl_xor(send, 4, 64);
    }

    zacc += __shfl_xor(zacc, 4, 64);
    zacc += __shfl_xor(zacc, 8, 64);
    zacc += __shfl_xor(zacc, 16, 64);
    zacc += __shfl_xor(zacc, 32, 64);

    out[(size_t)n * HD + h * DPH + t] = acc[0] / (zacc + 1e-6f);
}

extern "C" void kernel_launch(void* const* d_in, const int* in_sizes, int n_in,
                              void* d_out, int out_size, void* d_ws, size_t ws_size,
                              hipStream_t stream) {
    const float* x   = (const float*)d_in[0];
    const int*   src = (const int*)d_in[1];
    const int*   dst = (const int*)d_in[2];
    const float* Wq  = (const float*)d_in[3];
    const float* Wk  = (const float*)d_in[4];
    const float* Wv  = (const float*)d_in[5];
    float* out = (float*)d_out;

    unsigned short* Qb = (unsigned short*)d_ws;                // 6.4 MB
    unsigned* KV    = (unsigned*)(Qb + (size_t)N_NODES * HD);  // 12.8 MB
    uint4*    Wpk   = (uint4*)(KV + (size_t)N_NODES * HD);     // 48 KB
    unsigned* slab  = (unsigned*)(Wpk + 12 * 4 * 64);          // 14.45 MB
    int*      gcnt  = (int*)(slab + (size_t)NB * PB * SLAB_CAP); // 200 KB
    int*      ghist = gcnt + NB * PB;                          // 784 B
    int*      off   = ghist + NB;                              // 200 KB
    int*      esrc  = off + (N_NODES + 1);                     // 6.4 MB

    repack_w<<<12, 256, 0, stream>>>(Wq, Wk, Wv, Wpk, ghist);
    qkv_and_partition<<<FUSED_TOTAL, 256, 0, stream>>>(x, Wpk, src, dst,
                                                       Qb, KV, slab, gcnt, ghist);
    bucket_csr<<<NB, 256, 0, stream>>>(slab, gcnt, ghist, off, esrc);
    gather_csr<<<(N_NODES + 3) / 4, 256, 0, stream>>>(off, esrc, Qb, KV, out);
}